// Round 1
// baseline (344.137 us; speedup 1.0000x reference)
//
#include <hip/hip_runtime.h>

typedef __attribute__((ext_vector_type(8))) short short8;
typedef __attribute__((ext_vector_type(4))) float f32x4;
typedef __attribute__((ext_vector_type(4))) float float4v;
typedef __attribute__((ext_vector_type(4))) unsigned short ushort4v;

// RNE float -> bf16 payload
__device__ __forceinline__ unsigned short f2bf(float f) {
    union { float f; unsigned u; } x; x.f = f;
    unsigned r = x.u + 0x7FFFu + ((x.u >> 16) & 1u);
    return (unsigned short)(r >> 16);
}

// C[k][n] = s(k) * cos(pi * k * (2n+1) / (2N)), N = 512, ortho norm.
// Exact integer reduction mod 4N keeps cosf argument small & accurate.
__global__ __launch_bounds__(256) void make_dct_mat(unsigned short* __restrict__ Cm) {
    int idx = blockIdx.x * 256 + threadIdx.x;     // 0 .. 512*512-1
    int k = idx >> 9;
    int n = idx & 511;
    int m = (k * (2 * n + 1)) & 2047;             // mod 4N (N=512)
    float ang = (3.14159265358979323846f / 1024.0f) * (float)m;
    float s = (k == 0) ? 0.04419417382415922f : 0.0625f;  // 1/sqrt(512), sqrt(2/512)
    Cm[idx] = f2bf(s * cosf(ang));
}

// D[img] = A * B[img]^T   (all 512x512 row-major per image)
// A: bf16 DCT matrix (shared).  B: fp32 (stage 1) or bf16 (stage 2).
// 128x128 tile, BK=32, 4 waves (2x2), mfma_f32_16x16x32_bf16, m97-style 2-phase.
template <bool B_IS_F32, bool OUT_F32>
__global__ __launch_bounds__(256) void dct_gemm(
    const unsigned short* __restrict__ A,
    const void* __restrict__ Ball,
    void* __restrict__ Dall)
{
    __shared__ unsigned short As[128 * 32];   // 8 KB
    __shared__ unsigned short Bs[128 * 32];   // 8 KB

    // XCD-bijective swizzle: nwg = nimg*16, multiple of 8.
    int wg  = blockIdx.x;
    int cpx = gridDim.x >> 3;
    int swz = (wg & 7) * cpx + (wg >> 3);
    int img  = swz >> 4;
    int tile = swz & 15;
    int R0 = (tile >> 2) * 128;   // rows of C (output rows)
    int C0 = (tile & 3) * 128;    // rows of B (output cols)

    int t    = threadIdx.x;
    int lane = t & 63;
    int wid  = t >> 6;
    int wm   = wid >> 1;
    int wn   = wid & 1;

    f32x4 acc[4][4] = {};

    const size_t imgoff = (size_t)img * (512 * 512);

    // A staging: thread t covers row (h*64 + t/4), 16B slot (t&3); LDS linear t*16B.
    const unsigned short* gA = A + (size_t)(R0 + (t >> 2)) * 512 + (t & 3) * 8;

    for (int kt = 0; kt < 16; ++kt) {
        const int kk = kt * 32;
        __syncthreads();   // previous compute done reading LDS

        __builtin_amdgcn_global_load_lds(
            (const __attribute__((address_space(1))) void*)(gA + kk),
            (__attribute__((address_space(3))) void*)(As + t * 8), 16, 0, 0);
        __builtin_amdgcn_global_load_lds(
            (const __attribute__((address_space(1))) void*)(gA + 64 * 512 + kk),
            (__attribute__((address_space(3))) void*)(As + 2048 + t * 8), 16, 0, 0);

        if constexpr (B_IS_F32) {
            // reg-stage + convert: thread t: row j*32 + t/8, 4 floats at col (t&7)*4
            const float* B = (const float*)Ball + imgoff;
            #pragma unroll
            for (int j = 0; j < 4; ++j) {
                int row = j * 32 + (t >> 3);
                float4v v = *(const float4v*)(B + (size_t)(C0 + row) * 512 + kk + (t & 7) * 4);
                ushort4v p;
                p.x = f2bf(v.x); p.y = f2bf(v.y); p.z = f2bf(v.z); p.w = f2bf(v.w);
                *(ushort4v*)(Bs + row * 32 + (t & 7) * 4) = p;
            }
        } else {
            const unsigned short* B = (const unsigned short*)Ball + imgoff;
            const unsigned short* gB = B + (size_t)(C0 + (t >> 2)) * 512 + (t & 3) * 8 + kk;
            __builtin_amdgcn_global_load_lds(
                (const __attribute__((address_space(1))) void*)gB,
                (__attribute__((address_space(3))) void*)(Bs + t * 8), 16, 0, 0);
            __builtin_amdgcn_global_load_lds(
                (const __attribute__((address_space(1))) void*)(gB + 64 * 512),
                (__attribute__((address_space(3))) void*)(Bs + 2048 + t * 8), 16, 0, 0);
        }

        __syncthreads();   // staging complete (compiler drains vmcnt/lgkmcnt)

        short8 av[4], bv[4];
        #pragma unroll
        for (int f = 0; f < 4; ++f) {
            av[f] = *(const short8*)(As + (wm * 64 + f * 16 + (lane & 15)) * 32 + (lane >> 4) * 8);
            bv[f] = *(const short8*)(Bs + (wn * 64 + f * 16 + (lane & 15)) * 32 + (lane >> 4) * 8);
        }
        #pragma unroll
        for (int fm = 0; fm < 4; ++fm)
            #pragma unroll
            for (int fn = 0; fn < 4; ++fn)
                acc[fm][fn] = __builtin_amdgcn_mfma_f32_16x16x32_bf16(
                                  av[fm], bv[fn], acc[fm][fn], 0, 0, 0);
    }

    // epilogue: C/D layout col = lane&15, row = (lane>>4)*4 + reg
    int r0 = R0 + wm * 64 + (lane >> 4) * 4;
    int c0 = C0 + wn * 64 + (lane & 15);
    if constexpr (OUT_F32) {
        float* D = (float*)Dall + imgoff;
        #pragma unroll
        for (int fm = 0; fm < 4; ++fm)
            #pragma unroll
            for (int fn = 0; fn < 4; ++fn)
                #pragma unroll
                for (int r = 0; r < 4; ++r)
                    D[(size_t)(r0 + fm * 16 + r) * 512 + c0 + fn * 16] = acc[fm][fn][r];
    } else {
        unsigned short* D = (unsigned short*)Dall + imgoff;
        #pragma unroll
        for (int fm = 0; fm < 4; ++fm)
            #pragma unroll
            for (int fn = 0; fn < 4; ++fn)
                #pragma unroll
                for (int r = 0; r < 4; ++r)
                    D[(size_t)(r0 + fm * 16 + r) * 512 + c0 + fn * 16] = f2bf(acc[fm][fn][r]);
    }
}

extern "C" void kernel_launch(void* const* d_in, const int* in_sizes, int n_in,
                              void* d_out, int out_size, void* d_ws, size_t ws_size,
                              hipStream_t stream) {
    const float* x = (const float*)d_in[0];
    float* out = (float*)d_out;

    // ws layout: [0, 512KB) = C matrix bf16; [1MB, 1MB+128MB) = intermediate T' bf16
    unsigned short* Cm = (unsigned short*)d_ws;
    unsigned short* Tm = (unsigned short*)((char*)d_ws + (1 << 20));

    int nimg = in_sizes[0] / (512 * 512);   // 256

    make_dct_mat<<<dim3(1024), dim3(256), 0, stream>>>(Cm);
    // Stage 1: T'[b] = C * X[b]^T   (B = fp32, out = bf16)
    dct_gemm<true, false><<<dim3(nimg * 16), dim3(256), 0, stream>>>(Cm, (const void*)x, (void*)Tm);
    // Stage 2: Y[b] = C * T'[b]^T = C X C^T  (B = bf16, out = fp32)
    dct_gemm<false, true><<<dim3(nimg * 16), dim3(256), 0, stream>>>(Cm, (const void*)Tm, (void*)out);
}

// Round 2
// 340.650 us; speedup vs baseline: 1.0102x; 1.0102x over previous
//
#include <hip/hip_runtime.h>

typedef __attribute__((ext_vector_type(8))) short short8;
typedef __attribute__((ext_vector_type(4))) float f32x4;
typedef __attribute__((ext_vector_type(4))) float float4v;
typedef __attribute__((ext_vector_type(4))) unsigned short ushort4v;

// RNE float -> bf16 payload
__device__ __forceinline__ unsigned short f2bf(float f) {
    union { float f; unsigned u; } x; x.f = f;
    unsigned r = x.u + 0x7FFFu + ((x.u >> 16) & 1u);
    return (unsigned short)(r >> 16);
}

// C[k][n] = s(k) * cos(pi * k * (2n+1) / (2N)), N = 512, ortho norm.
__global__ __launch_bounds__(256) void make_dct_mat(unsigned short* __restrict__ Cm) {
    int idx = blockIdx.x * 256 + threadIdx.x;     // 0 .. 512*512-1
    int k = idx >> 9;
    int n = idx & 511;
    int m = (k * (2 * n + 1)) & 2047;             // mod 4N (N=512)
    float ang = (3.14159265358979323846f / 1024.0f) * (float)m;
    float s = (k == 0) ? 0.04419417382415922f : 0.0625f;  // 1/sqrt(512), sqrt(2/512)
    Cm[idx] = f2bf(s * cosf(ang));
}

// D[img] = A * B[img]^T   (all 512x512 row-major per image)
// 128x128 tile, BK=32, 4 waves (2x2), mfma_f32_16x16x32_bf16.
// Pipelined 1-deep double-buffer (one barrier per K-step) + both-sides
// 16B-slot swizzle: LDS (row, slotL) holds global (row, slotL ^ ((row>>1)&3)).
template <bool B_IS_F32, bool OUT_F32>
__global__ __launch_bounds__(256) void dct_gemm(
    const unsigned short* __restrict__ A,
    const void* __restrict__ Ball,
    void* __restrict__ Dall)
{
    __shared__ unsigned short As[2][128 * 32];   // 2 x 8 KB
    __shared__ unsigned short Bs[2][128 * 32];   // 2 x 8 KB

    // XCD-bijective swizzle: nwg = nimg*16, multiple of 8.
    int wg  = blockIdx.x;
    int cpx = gridDim.x >> 3;
    int swz = (wg & 7) * cpx + (wg >> 3);
    int img  = swz >> 4;
    int tile = swz & 15;
    int R0 = (tile >> 2) * 128;   // rows of C (output rows)
    int C0 = (tile & 3) * 128;    // rows of B (output cols)

    int t    = threadIdx.x;
    int lane = t & 63;
    int wid  = t >> 6;
    int wm   = wid >> 1;
    int wn   = wid & 1;

    f32x4 acc[4][4] = {};

    const size_t imgoff = (size_t)img * (512 * 512);

    // --- staging source addresses (pre-swizzled slot) ---
    // gload_lds: thread t -> LDS linear t*16B -> (row = t>>2, slotL = t&3);
    // source slot = slotL ^ sw(row), sw(row) = (row>>1)&3 = (t>>3)&3.
    const int aslot = ((t & 3) ^ ((t >> 3) & 3)) * 8;   // element offset within 32-col chunk
    const unsigned short* gA = A + (size_t)(R0 + (t >> 2)) * 512 + aslot;
    const unsigned short* gB16 = nullptr;
    if constexpr (!B_IS_F32)
        gB16 = (const unsigned short*)Ball + imgoff + (size_t)(C0 + (t >> 2)) * 512 + aslot;

    auto stageA = [&](int buf, int kk) {
        __builtin_amdgcn_global_load_lds(
            (const __attribute__((address_space(1))) void*)(gA + kk),
            (__attribute__((address_space(3))) void*)(&As[buf][t * 8]), 16, 0, 0);
        __builtin_amdgcn_global_load_lds(
            (const __attribute__((address_space(1))) void*)(gA + 64 * 512 + kk),
            (__attribute__((address_space(3))) void*)(&As[buf][2048 + t * 8]), 16, 0, 0);
    };
    auto stageB16 = [&](int buf, int kk) {
        __builtin_amdgcn_global_load_lds(
            (const __attribute__((address_space(1))) void*)(gB16 + kk),
            (__attribute__((address_space(3))) void*)(&Bs[buf][t * 8]), 16, 0, 0);
        __builtin_amdgcn_global_load_lds(
            (const __attribute__((address_space(1))) void*)(gB16 + 64 * 512 + kk),
            (__attribute__((address_space(3))) void*)(&Bs[buf][2048 + t * 8]), 16, 0, 0);
    };

    // fp32 B path: issue loads early, convert + ds_write late (T14 split).
    float4v breg[4];
    auto loadBf32 = [&](int kk) {
        const float* B = (const float*)Ball + imgoff;
        #pragma unroll
        for (int j = 0; j < 4; ++j) {
            int row = j * 32 + (t >> 3);
            breg[j] = *(const float4v*)(B + (size_t)(C0 + row) * 512 + kk + (t & 7) * 4);
        }
    };
    auto writeBf32 = [&](int buf) {
        #pragma unroll
        for (int j = 0; j < 4; ++j) {
            int row = j * 32 + (t >> 3);
            int slotL = ((t & 7) >> 1) ^ ((row >> 1) & 3);
            int sidx = row * 32 + slotL * 8 + (t & 7 & 1) * 4;
            ushort4v p;
            p.x = f2bf(breg[j].x); p.y = f2bf(breg[j].y);
            p.z = f2bf(breg[j].z); p.w = f2bf(breg[j].w);
            *(ushort4v*)(&Bs[buf][sidx]) = p;
        }
    };

    auto compute = [&](int buf) {
        const int roff = ((lane >> 4) ^ ((lane >> 1) & 3)) * 8;  // swizzled read slot
        short8 av[4], bv[4];
        #pragma unroll
        for (int f = 0; f < 4; ++f) {
            av[f] = *(const short8*)(&As[buf][(wm * 64 + f * 16 + (lane & 15)) * 32 + roff]);
            bv[f] = *(const short8*)(&Bs[buf][(wn * 64 + f * 16 + (lane & 15)) * 32 + roff]);
        }
        #pragma unroll
        for (int fm = 0; fm < 4; ++fm)
            #pragma unroll
            for (int fn = 0; fn < 4; ++fn)
                acc[fm][fn] = __builtin_amdgcn_mfma_f32_16x16x32_bf16(
                                  av[fm], bv[fn], acc[fm][fn], 0, 0, 0);
    };

    // --- prologue: stage tile 0 into buf 0 ---
    stageA(0, 0);
    if constexpr (B_IS_F32) { loadBf32(0); writeBf32(0); }
    else                    { stageB16(0, 0); }
    __syncthreads();

    int buf = 0;
    for (int kt = 0; kt < 16; ++kt) {
        const int kk2 = (kt + 1) * 32;
        if (kt < 15) {
            stageA(buf ^ 1, kk2);              // issue next-tile loads first
            if constexpr (B_IS_F32) loadBf32(kk2);
            else                    stageB16(buf ^ 1, kk2);
        }
        compute(buf);                          // ds_read + MFMA on current
        if constexpr (B_IS_F32) {
            if (kt < 15) writeBf32(buf ^ 1);   // write-late (after compute)
        }
        __syncthreads();                       // drains vm+lgkm: next tile ready
        buf ^= 1;
    }

    // epilogue: C/D layout col = lane&15, row = (lane>>4)*4 + reg
    int r0 = R0 + wm * 64 + (lane >> 4) * 4;
    int c0 = C0 + wn * 64 + (lane & 15);
    if constexpr (OUT_F32) {
        float* D = (float*)Dall + imgoff;
        #pragma unroll
        for (int fm = 0; fm < 4; ++fm)
            #pragma unroll
            for (int fn = 0; fn < 4; ++fn)
                #pragma unroll
                for (int r = 0; r < 4; ++r)
                    D[(size_t)(r0 + fm * 16 + r) * 512 + c0 + fn * 16] = acc[fm][fn][r];
    } else {
        unsigned short* D = (unsigned short*)Dall + imgoff;
        #pragma unroll
        for (int fm = 0; fm < 4; ++fm)
            #pragma unroll
            for (int fn = 0; fn < 4; ++fn)
                #pragma unroll
                for (int r = 0; r < 4; ++r)
                    D[(size_t)(r0 + fm * 16 + r) * 512 + c0 + fn * 16] = f2bf(acc[fm][fn][r]);
    }
}

extern "C" void kernel_launch(void* const* d_in, const int* in_sizes, int n_in,
                              void* d_out, int out_size, void* d_ws, size_t ws_size,
                              hipStream_t stream) {
    const float* x = (const float*)d_in[0];
    float* out = (float*)d_out;

    // ws layout: [0, 512KB) = C matrix bf16; [1MB, 1MB+128MB) = intermediate T' bf16
    unsigned short* Cm = (unsigned short*)d_ws;
    unsigned short* Tm = (unsigned short*)((char*)d_ws + (1 << 20));

    int nimg = in_sizes[0] / (512 * 512);   // 256

    make_dct_mat<<<dim3(1024), dim3(256), 0, stream>>>(Cm);
    // Stage 1: T'[b] = C * X[b]^T   (B = fp32, out = bf16)
    dct_gemm<true, false><<<dim3(nimg * 16), dim3(256), 0, stream>>>(Cm, (const void*)x, (void*)Tm);
    // Stage 2: Y[b] = C * T'[b]^T = C X C^T  (B = bf16, out = fp32)
    dct_gemm<false, true><<<dim3(nimg * 16), dim3(256), 0, stream>>>(Cm, (const void*)Tm, (void*)out);
}

// Round 3
// 335.629 us; speedup vs baseline: 1.0253x; 1.0150x over previous
//
#include <hip/hip_runtime.h>
#include <hip/hip_bf16.h>

typedef __attribute__((ext_vector_type(8))) short short8;
typedef __attribute__((ext_vector_type(4))) float f32x4;
typedef __attribute__((ext_vector_type(4))) float float4v;

// RNE float -> bf16 payload (used in matrix gen + epilogue)
__device__ __forceinline__ unsigned short f2bf(float f) {
    union { float f; unsigned u; } x; x.f = f;
    unsigned r = x.u + 0x7FFFu + ((x.u >> 16) & 1u);
    return (unsigned short)(r >> 16);
}

// C[k][n] = s(k) * cos(pi * k * (2n+1) / (2N)), N = 512, ortho norm.
__global__ __launch_bounds__(256) void make_dct_mat(unsigned short* __restrict__ Cm) {
    int idx = blockIdx.x * 256 + threadIdx.x;     // 0 .. 512*512-1
    int k = idx >> 9;
    int n = idx & 511;
    int m = (k * (2 * n + 1)) & 2047;             // mod 4N (N=512)
    float ang = (3.14159265358979323846f / 1024.0f) * (float)m;
    float s = (k == 0) ? 0.04419417382415922f : 0.0625f;  // 1/sqrt(512), sqrt(2/512)
    Cm[idx] = f2bf(s * cosf(ang));
}

// counted-vmcnt barrier: wait until <= N vmem ops outstanding, then s_barrier.
#define SYNC_VM(N) asm volatile("s_waitcnt vmcnt(" #N ")\n\ts_barrier" ::: "memory")

#define GLD16(g, l) __builtin_amdgcn_global_load_lds( \
    (const __attribute__((address_space(1))) void*)(g), \
    (__attribute__((address_space(3))) void*)(l), 16, 0, 0)

// D[img] = A * B[img]^T   (512x512 row-major per image)
// 128x128 tile, BK=32, 4 waves (2x2), mfma_f32_16x16x32_bf16.
// 3-slot LDS ring, prefetch distance 2, ONE raw s_barrier + counted vmcnt per
// K-step (T3+T4). Both-sides XOR slot swizzle keeps all LDS reads conflict-free.
template <bool B_IS_F32, bool OUT_F32>
__global__ __launch_bounds__(256) void dct_gemm(
    const unsigned short* __restrict__ A,
    const void* __restrict__ Ball,
    void* __restrict__ Dall)
{
    __shared__ unsigned short As[3][128 * 32];                       // 3 x 8 KB
    __shared__ unsigned short Bs[3][B_IS_F32 ? 128 * 64 : 128 * 32]; // 3 x 16 KB (fp32) / 8 KB

    // XCD-bijective swizzle: nwg = nimg*16, multiple of 8.
    int wg  = blockIdx.x;
    int cpx = gridDim.x >> 3;
    int swz = (wg & 7) * cpx + (wg >> 3);
    int img  = swz >> 4;
    int tile = swz & 15;
    int R0 = (tile >> 2) * 128;   // output rows (rows of C)
    int C0 = (tile & 3) * 128;    // output cols (rows of B)

    int t    = threadIdx.x;
    int lane = t & 63;
    int wid  = t >> 6;
    int wm   = wid >> 1;
    int wn   = wid & 1;

    f32x4 acc[4][4] = {};

    const size_t imgoff = (size_t)img * (512 * 512);

    // ---- staging source addresses (pre-swizzled 16B slot) ----
    // A/bf16-B tile [128][32] bf16: 4 slots/row, slotG = slotL ^ ((row>>1)&3).
    const int aslot = ((t & 3) ^ ((t >> 3) & 3)) * 8;
    const unsigned short* gA = A + (size_t)(R0 + (t >> 2)) * 512 + aslot;
    // fp32-B tile [128][32] f32: 8 slots/row (16B), slotG = slotL ^ (row&7).
    const int bslot = (t & 7) ^ ((t >> 3) & 7);
    const float* gBf = nullptr;
    const unsigned short* gB16 = nullptr;
    if constexpr (B_IS_F32)
        gBf = (const float*)Ball + imgoff + (size_t)(C0 + (t >> 3)) * 512 + bslot * 4;
    else
        gB16 = (const unsigned short*)Ball + imgoff + (size_t)(C0 + (t >> 2)) * 512 + aslot;

    auto stage = [&](int s, int kk) {
        GLD16(gA + kk,            &As[s][t * 8]);
        GLD16(gA + 64 * 512 + kk, &As[s][2048 + t * 8]);
        if constexpr (B_IS_F32) {
            float* Bf = (float*)&Bs[s][0];
            #pragma unroll
            for (int g = 0; g < 4; ++g)
                GLD16(gBf + (size_t)g * 32 * 512 + kk, Bf + g * 1024 + t * 4);
        } else {
            GLD16(gB16 + kk,            &Bs[s][t * 8]);
            GLD16(gB16 + 64 * 512 + kk, &Bs[s][2048 + t * 8]);
        }
    };

    auto compute = [&](int s) {
        const int roff = ((lane >> 4) ^ ((lane >> 1) & 3)) * 8;
        short8 av[4], bv[4];
        #pragma unroll
        for (int f = 0; f < 4; ++f)
            av[f] = *(const short8*)(&As[s][(wm * 64 + f * 16 + (lane & 15)) * 32 + roff]);
        if constexpr (B_IS_F32) {
            const float* Bf = (const float*)&Bs[s][0];
            const int s0 = (2 * (lane >> 4))     ^ (lane & 7);
            const int s1 = (2 * (lane >> 4) + 1) ^ (lane & 7);
            #pragma unroll
            for (int f = 0; f < 4; ++f) {
                int row = wn * 64 + f * 16 + (lane & 15);
                float4v lo = *(const float4v*)(Bf + row * 32 + s0 * 4);
                float4v hi = *(const float4v*)(Bf + row * 32 + s1 * 4);
                union { short8 s8; __hip_bfloat162 h2[4]; } u;
                u.h2[0] = __float22bfloat162_rn(float2{lo.x, lo.y});
                u.h2[1] = __float22bfloat162_rn(float2{lo.z, lo.w});
                u.h2[2] = __float22bfloat162_rn(float2{hi.x, hi.y});
                u.h2[3] = __float22bfloat162_rn(float2{hi.z, hi.w});
                bv[f] = u.s8;
            }
        } else {
            #pragma unroll
            for (int f = 0; f < 4; ++f)
                bv[f] = *(const short8*)(&Bs[s][(wn * 64 + f * 16 + (lane & 15)) * 32 + roff]);
        }
        __builtin_amdgcn_s_setprio(1);
        #pragma unroll
        for (int fm = 0; fm < 4; ++fm)
            #pragma unroll
            for (int fn = 0; fn < 4; ++fn)
                acc[fm][fn] = __builtin_amdgcn_mfma_f32_16x16x32_bf16(
                                  av[fm], bv[fn], acc[fm][fn], 0, 0, 0);
        __builtin_amdgcn_s_setprio(0);
    };

    // ---- prologue: tiles 0,1 in flight; wait tile0 (keep tile1 outstanding) ----
    stage(0, 0);
    stage(1, 32);
    if constexpr (B_IS_F32) SYNC_VM(6); else SYNC_VM(4);

    // ---- main loop: 16 K-steps, one barrier each, vmcnt never drained to 0 ----
    #pragma unroll
    for (int kt = 0; kt < 16; ++kt) {
        if (kt < 14) stage((kt + 2) % 3, (kt + 2) * 32);
        compute(kt % 3);
        if (kt < 15) {
            if (kt <= 13) { if constexpr (B_IS_F32) SYNC_VM(6); else SYNC_VM(4); }
            else          { SYNC_VM(0); }
        }
    }

    // ---- epilogue: C/D layout col = lane&15, row = (lane>>4)*4 + reg ----
    int r0 = R0 + wm * 64 + (lane >> 4) * 4;
    int c0 = C0 + wn * 64 + (lane & 15);
    if constexpr (OUT_F32) {
        float* D = (float*)Dall + imgoff;
        #pragma unroll
        for (int fm = 0; fm < 4; ++fm)
            #pragma unroll
            for (int fn = 0; fn < 4; ++fn)
                #pragma unroll
                for (int r = 0; r < 4; ++r)
                    D[(size_t)(r0 + fm * 16 + r) * 512 + c0 + fn * 16] = acc[fm][fn][r];
    } else {
        unsigned short* D = (unsigned short*)Dall + imgoff;
        #pragma unroll
        for (int fm = 0; fm < 4; ++fm)
            #pragma unroll
            for (int fn = 0; fn < 4; ++fn)
                #pragma unroll
                for (int r = 0; r < 4; ++r)
                    D[(size_t)(r0 + fm * 16 + r) * 512 + c0 + fn * 16] = f2bf(acc[fm][fn][r]);
    }
}

extern "C" void kernel_launch(void* const* d_in, const int* in_sizes, int n_in,
                              void* d_out, int out_size, void* d_ws, size_t ws_size,
                              hipStream_t stream) {
    const float* x = (const float*)d_in[0];
    float* out = (float*)d_out;

    // ws layout: [0, 512KB) = C matrix bf16; [1MB, 1MB+128MB) = intermediate T' bf16
    unsigned short* Cm = (unsigned short*)d_ws;
    unsigned short* Tm = (unsigned short*)((char*)d_ws + (1 << 20));

    int nimg = in_sizes[0] / (512 * 512);   // 256

    make_dct_mat<<<dim3(1024), dim3(256), 0, stream>>>(Cm);
    // Stage 1: T'[b] = C * X[b]^T   (B = fp32 in LDS, out = bf16)
    dct_gemm<true, false><<<dim3(nimg * 16), dim3(256), 0, stream>>>(Cm, (const void*)x, (void*)Tm);
    // Stage 2: Y[b] = C * T'[b]^T = C X C^T  (B = bf16, out = fp32)
    dct_gemm<false, true><<<dim3(nimg * 16), dim3(256), 0, stream>>>(Cm, (const void*)Tm, (void*)out);
}

// Round 4
// 311.294 us; speedup vs baseline: 1.1055x; 1.0782x over previous
//
#include <hip/hip_runtime.h>
#include <hip/hip_bf16.h>

typedef __attribute__((ext_vector_type(8))) short short8;
typedef __attribute__((ext_vector_type(4))) float f32x4;
typedef __attribute__((ext_vector_type(4))) float float4v;
typedef __attribute__((ext_vector_type(8))) unsigned short ushort8;

// RNE float -> bf16 payload
__device__ __forceinline__ unsigned short f2bf(float f) {
    union { float f; unsigned u; } x; x.f = f;
    unsigned r = x.u + 0x7FFFu + ((x.u >> 16) & 1u);
    return (unsigned short)(r >> 16);
}

// C[k][n] = s(k) * cos(pi * k * (2n+1) / (2N)), N = 512, ortho norm.
__global__ __launch_bounds__(256) void make_dct_mat(unsigned short* __restrict__ Cm) {
    int idx = blockIdx.x * 256 + threadIdx.x;     // 0 .. 512*512-1
    int k = idx >> 9;
    int n = idx & 511;
    int m = (k * (2 * n + 1)) & 2047;             // mod 4N (N=512)
    float ang = (3.14159265358979323846f / 1024.0f) * (float)m;
    float s = (k == 0) ? 0.04419417382415922f : 0.0625f;  // 1/sqrt(512), sqrt(2/512)
    Cm[idx] = f2bf(s * cosf(ang));
}

#define GLD16(g, l) __builtin_amdgcn_global_load_lds( \
    (const __attribute__((address_space(1))) void*)(g), \
    (__attribute__((address_space(3))) void*)(l), 16, 0, 0)

#define SYNC_VM0()   asm volatile("s_waitcnt vmcnt(0)\n\ts_barrier" ::: "memory")
#define SYNC_FULL()  asm volatile("s_waitcnt vmcnt(0) lgkmcnt(0)\n\ts_barrier" ::: "memory")

// D[img] = A * B[img]^T   (512x512 row-major per image)
// 128x128 tile, BK=64 (two proven [128][32] swizzled sub-tiles), 4 waves (2x2),
// 2-slot double buffer, prefetch issued BEFORE compute, one barrier per K-step.
template <bool B_IS_F32, bool OUT_F32>
__device__ __forceinline__ void dct_gemm_body(
    const unsigned short* __restrict__ A,
    const void* __restrict__ Ball,
    void* __restrict__ Dall)
{
    // [slot][ksub][128*32]: each ksub sub-tile is the round-2 proven layout.
    __shared__ unsigned short As[2][2][128 * 32];   // 32 KB
    __shared__ unsigned short Bs[2][2][128 * 32];   // 32 KB

    // XCD-bijective swizzle: nwg = nimg*16, multiple of 8.
    int wg  = blockIdx.x;
    int cpx = gridDim.x >> 3;
    int swz = (wg & 7) * cpx + (wg >> 3);
    int img  = swz >> 4;
    int tile = swz & 15;
    int R0 = (tile >> 2) * 128;   // output rows (rows of C)
    int C0 = (tile & 3) * 128;    // output cols (rows of B)

    int t    = threadIdx.x;
    int lane = t & 63;
    int wid  = t >> 6;
    int wm   = wid >> 1;
    int wn   = wid & 1;

    f32x4 acc[4][4] = {};

    const size_t imgoff = (size_t)img * (512 * 512);

    // Proven round-2 swizzle: LDS (row, slotL) holds global slot slotL ^ ((row>>1)&3).
    // GLD16 dest linear t*16B -> (row = t>>2, slotL = t&3); source slot pre-XORed.
    const int aslot = ((t & 3) ^ ((t >> 3) & 3)) * 8;   // element offset in 32-col chunk
    const unsigned short* gA = A + (size_t)(R0 + (t >> 2)) * 512 + aslot;
    const unsigned short* gB16 = nullptr;
    const float* gBf = nullptr;
    if constexpr (B_IS_F32)
        gBf = (const float*)Ball + imgoff + (size_t)(C0 + (t >> 2)) * 512 + aslot;
    else
        gB16 = (const unsigned short*)Ball + imgoff + (size_t)(C0 + (t >> 2)) * 512 + aslot;

    auto stageA = [&](int sl, int kk) {
        #pragma unroll
        for (int ks = 0; ks < 2; ++ks) {
            GLD16(gA + kk + ks * 32,            &As[sl][ks][t * 8]);
            GLD16(gA + kk + ks * 32 + 64 * 512, &As[sl][ks][2048 + t * 8]);
        }
    };
    auto stageB16 = [&](int sl, int kk) {
        #pragma unroll
        for (int ks = 0; ks < 2; ++ks) {
            GLD16(gB16 + kk + ks * 32,            &Bs[sl][ks][t * 8]);
            GLD16(gB16 + kk + ks * 32 + 64 * 512, &Bs[sl][ks][2048 + t * 8]);
        }
    };

    // Stage-1 fp32 B: issue loads early (before compute), cvt + ds_write late.
    float4v breg[2][2][2];   // [ksub][row-half][lo/hi]
    auto loadBf32 = [&](int kk) {
        #pragma unroll
        for (int ks = 0; ks < 2; ++ks)
            #pragma unroll
            for (int h = 0; h < 2; ++h) {
                const float* p = gBf + kk + ks * 32 + (size_t)h * 64 * 512;
                breg[ks][h][0] = *(const float4v*)(p);
                breg[ks][h][1] = *(const float4v*)(p + 4);
            }
    };
    auto writeBf32 = [&](int sl) {
        #pragma unroll
        for (int ks = 0; ks < 2; ++ks)
            #pragma unroll
            for (int h = 0; h < 2; ++h) {
                union { ushort8 u8; __hip_bfloat162 h2[4]; } u;
                u.h2[0] = __float22bfloat162_rn(float2{breg[ks][h][0].x, breg[ks][h][0].y});
                u.h2[1] = __float22bfloat162_rn(float2{breg[ks][h][0].z, breg[ks][h][0].w});
                u.h2[2] = __float22bfloat162_rn(float2{breg[ks][h][1].x, breg[ks][h][1].y});
                u.h2[3] = __float22bfloat162_rn(float2{breg[ks][h][1].z, breg[ks][h][1].w});
                *(ushort8*)(&Bs[sl][ks][h * 2048 + t * 8]) = u.u8;   // linear: conflict-free
            }
    };

    auto compute = [&](int sl) {
        const int roff = ((lane >> 4) ^ ((lane >> 1) & 3)) * 8;   // proven read swizzle
        short8 av[4][2], bv[4][2];
        #pragma unroll
        for (int m = 0; m < 4; ++m)
            #pragma unroll
            for (int ks = 0; ks < 2; ++ks)
                av[m][ks] = *(const short8*)(&As[sl][ks][(wm * 64 + m * 16 + (lane & 15)) * 32 + roff]);
        #pragma unroll
        for (int n = 0; n < 4; ++n)
            #pragma unroll
            for (int ks = 0; ks < 2; ++ks)
                bv[n][ks] = *(const short8*)(&Bs[sl][ks][(wn * 64 + n * 16 + (lane & 15)) * 32 + roff]);
        __builtin_amdgcn_s_setprio(1);
        #pragma unroll
        for (int m = 0; m < 4; ++m)
            #pragma unroll
            for (int n = 0; n < 4; ++n)
                #pragma unroll
                for (int ks = 0; ks < 2; ++ks)
                    acc[m][n] = __builtin_amdgcn_mfma_f32_16x16x32_bf16(
                                    av[m][ks], bv[n][ks], acc[m][n], 0, 0, 0);
        __builtin_amdgcn_s_setprio(0);
    };

    // ---- prologue: stage tile 0 ----
    stageA(0, 0);
    if constexpr (B_IS_F32) {
        loadBf32(0);
        writeBf32(0);        // compiler inserts vmcnt wait for breg
        SYNC_FULL();
    } else {
        stageB16(0, 0);
        SYNC_VM0();
    }

    // ---- main loop: 8 K-steps, one barrier each, prefetch-before-compute ----
    #pragma unroll
    for (int kt = 0; kt < 8; ++kt) {
        const int sl = kt & 1;
        if (kt < 7) {
            stageA(sl ^ 1, (kt + 1) * 64);
            if constexpr (B_IS_F32) loadBf32((kt + 1) * 64);
            else                    stageB16(sl ^ 1, (kt + 1) * 64);
        }
        compute(sl);
        if (kt < 7) {
            if constexpr (B_IS_F32) {
                writeBf32(sl ^ 1);   // write-late: after compute, before barrier
                SYNC_FULL();
            } else {
                SYNC_VM0();
            }
        }
    }

    // ---- epilogue: C/D layout col = lane&15, row = (lane>>4)*4 + reg ----
    int r0 = R0 + wm * 64 + (lane >> 4) * 4;
    int c0 = C0 + wn * 64 + (lane & 15);
    if constexpr (OUT_F32) {
        float* D = (float*)Dall + imgoff;
        #pragma unroll
        for (int fm = 0; fm < 4; ++fm)
            #pragma unroll
            for (int fn = 0; fn < 4; ++fn)
                #pragma unroll
                for (int r = 0; r < 4; ++r)
                    D[(size_t)(r0 + fm * 16 + r) * 512 + c0 + fn * 16] = acc[fm][fn][r];
    } else {
        unsigned short* D = (unsigned short*)Dall + imgoff;
        #pragma unroll
        for (int fm = 0; fm < 4; ++fm)
            #pragma unroll
            for (int fn = 0; fn < 4; ++fn)
                #pragma unroll
                for (int r = 0; r < 4; ++r)
                    D[(size_t)(r0 + fm * 16 + r) * 512 + c0 + fn * 16] = f2bf(acc[fm][fn][r]);
    }
}

__global__ __launch_bounds__(256) void dct_gemm_s1(
    const unsigned short* __restrict__ A, const float* __restrict__ B,
    unsigned short* __restrict__ D) {
    dct_gemm_body<true, false>(A, B, D);
}

__global__ __launch_bounds__(256) void dct_gemm_s2(
    const unsigned short* __restrict__ A, const unsigned short* __restrict__ B,
    float* __restrict__ D) {
    dct_gemm_body<false, true>(A, B, D);
}

extern "C" void kernel_launch(void* const* d_in, const int* in_sizes, int n_in,
                              void* d_out, int out_size, void* d_ws, size_t ws_size,
                              hipStream_t stream) {
    const float* x = (const float*)d_in[0];
    float* out = (float*)d_out;

    // ws layout: [0, 512KB) = C matrix bf16; [1MB, 1MB+128MB) = intermediate T' bf16
    unsigned short* Cm = (unsigned short*)d_ws;
    unsigned short* Tm = (unsigned short*)((char*)d_ws + (1 << 20));

    int nimg = in_sizes[0] / (512 * 512);   // 256

    make_dct_mat<<<dim3(1024), dim3(256), 0, stream>>>(Cm);
    // Stage 1: T'[b] = C * X[b]^T   (B = fp32 -> cvt in regs -> bf16 LDS, out = bf16)
    dct_gemm_s1<<<dim3(nimg * 16), dim3(256), 0, stream>>>(Cm, x, Tm);
    // Stage 2: Y[b] = C * T'[b]^T = C X C^T  (B = bf16 via global_load_lds, out = fp32)
    dct_gemm_s2<<<dim3(nimg * 16), dim3(256), 0, stream>>>(Cm, Tm, out);
}

// Round 5
// 310.844 us; speedup vs baseline: 1.1071x; 1.0014x over previous
//
#include <hip/hip_runtime.h>
#include <hip/hip_bf16.h>

typedef __attribute__((ext_vector_type(8))) short short8;
typedef __attribute__((ext_vector_type(4))) float f32x4;
typedef __attribute__((ext_vector_type(4))) float float4v;
typedef __attribute__((ext_vector_type(8))) unsigned short ushort8;

// RNE float -> bf16 payload
__device__ __forceinline__ unsigned short f2bf(float f) {
    union { float f; unsigned u; } x; x.f = f;
    unsigned r = x.u + 0x7FFFu + ((x.u >> 16) & 1u);
    return (unsigned short)(r >> 16);
}

// C[k][n] = s(k) * cos(pi * k * (2n+1) / (2N)), N = 512, ortho norm.
__global__ __launch_bounds__(256) void make_dct_mat(unsigned short* __restrict__ Cm) {
    int idx = blockIdx.x * 256 + threadIdx.x;     // 0 .. 512*512-1
    int k = idx >> 9;
    int n = idx & 511;
    int m = (k * (2 * n + 1)) & 2047;             // mod 4N (N=512)
    float ang = (3.14159265358979323846f / 1024.0f) * (float)m;
    float s = (k == 0) ? 0.04419417382415922f : 0.0625f;  // 1/sqrt(512), sqrt(2/512)
    Cm[idx] = f2bf(s * cosf(ang));
}

#define GLD16(g, l) __builtin_amdgcn_global_load_lds( \
    (const __attribute__((address_space(1))) void*)(g), \
    (__attribute__((address_space(3))) void*)(l), 16, 0, 0)

#define SYNC_VM0()   asm volatile("s_waitcnt vmcnt(0)\n\ts_barrier" ::: "memory")
#define SYNC_FULL()  asm volatile("s_waitcnt vmcnt(0) lgkmcnt(0)\n\ts_barrier" ::: "memory")

// D[img] = A * B[img]^T   (512x512 row-major per image)
// 128x128 tile, BK=64 (two proven [128][32] swizzled sub-tiles), 4 waves (2x2),
// 2-slot double buffer, prefetch issued BEFORE compute, one barrier per K-step.
template <bool B_IS_F32, bool OUT_F32>
__device__ __forceinline__ void dct_gemm_body(
    const unsigned short* __restrict__ A,
    const void* __restrict__ Ball,
    void* __restrict__ Dall)
{
    // [slot][ksub][128*32]: each ksub sub-tile is the round-2 proven layout.
    __shared__ unsigned short As[2][2][128 * 32];   // 32 KB
    __shared__ unsigned short Bs[2][2][128 * 32];   // 32 KB

    // XCD-bijective swizzle: nwg = nimg*16, multiple of 8.
    int wg  = blockIdx.x;
    int cpx = gridDim.x >> 3;
    int swz = (wg & 7) * cpx + (wg >> 3);
    int img  = swz >> 4;
    int tile = swz & 15;
    int R0 = (tile >> 2) * 128;   // output rows (rows of C)
    int C0 = (tile & 3) * 128;    // output cols (rows of B)

    int t    = threadIdx.x;
    int lane = t & 63;
    int wid  = t >> 6;
    int wm   = wid >> 1;
    int wn   = wid & 1;

    f32x4 acc[4][4] = {};

    const size_t imgoff = (size_t)img * (512 * 512);

    // Proven round-2 swizzle: LDS (row, slotL) holds global slot slotL ^ ((row>>1)&3).
    // GLD16 dest linear t*16B -> (row = t>>2, slotL = t&3); source slot pre-XORed.
    const int aslot = ((t & 3) ^ ((t >> 3) & 3)) * 8;   // element offset in 32-col chunk
    const unsigned short* gA = A + (size_t)(R0 + (t >> 2)) * 512 + aslot;
    const unsigned short* gB16 = nullptr;
    const float* gBf = nullptr;
    if constexpr (B_IS_F32)
        gBf = (const float*)Ball + imgoff + (size_t)(C0 + (t >> 2)) * 512 + aslot;
    else
        gB16 = (const unsigned short*)Ball + imgoff + (size_t)(C0 + (t >> 2)) * 512 + aslot;

    auto stageA = [&](int sl, int kk) {
        #pragma unroll
        for (int ks = 0; ks < 2; ++ks) {
            GLD16(gA + kk + ks * 32,            &As[sl][ks][t * 8]);
            GLD16(gA + kk + ks * 32 + 64 * 512, &As[sl][ks][2048 + t * 8]);
        }
    };
    auto stageB16 = [&](int sl, int kk) {
        #pragma unroll
        for (int ks = 0; ks < 2; ++ks) {
            GLD16(gB16 + kk + ks * 32,            &Bs[sl][ks][t * 8]);
            GLD16(gB16 + kk + ks * 32 + 64 * 512, &Bs[sl][ks][2048 + t * 8]);
        }
    };

    // Stage-1 fp32 B: issue loads early (before compute), cvt + ds_write late.
    float4v breg[2][2][2];   // [ksub][row-half][lo/hi]
    auto loadBf32 = [&](int kk) {
        #pragma unroll
        for (int ks = 0; ks < 2; ++ks)
            #pragma unroll
            for (int h = 0; h < 2; ++h) {
                const float* p = gBf + kk + ks * 32 + (size_t)h * 64 * 512;
                breg[ks][h][0] = *(const float4v*)(p);
                breg[ks][h][1] = *(const float4v*)(p + 4);
            }
    };
    auto writeBf32 = [&](int sl) {
        #pragma unroll
        for (int ks = 0; ks < 2; ++ks)
            #pragma unroll
            for (int h = 0; h < 2; ++h) {
                union { ushort8 u8; __hip_bfloat162 h2[4]; } u;
                u.h2[0] = __float22bfloat162_rn(float2{breg[ks][h][0].x, breg[ks][h][0].y});
                u.h2[1] = __float22bfloat162_rn(float2{breg[ks][h][0].z, breg[ks][h][0].w});
                u.h2[2] = __float22bfloat162_rn(float2{breg[ks][h][1].x, breg[ks][h][1].y});
                u.h2[3] = __float22bfloat162_rn(float2{breg[ks][h][1].z, breg[ks][h][1].w});
                *(ushort8*)(&Bs[sl][ks][h * 2048 + t * 8]) = u.u8;   // linear: conflict-free
            }
    };

    auto compute = [&](int sl) {
        const int roff = ((lane >> 4) ^ ((lane >> 1) & 3)) * 8;   // proven read swizzle
        short8 av[4][2], bv[4][2];
        #pragma unroll
        for (int m = 0; m < 4; ++m)
            #pragma unroll
            for (int ks = 0; ks < 2; ++ks)
                av[m][ks] = *(const short8*)(&As[sl][ks][(wm * 64 + m * 16 + (lane & 15)) * 32 + roff]);
        #pragma unroll
        for (int n = 0; n < 4; ++n)
            #pragma unroll
            for (int ks = 0; ks < 2; ++ks)
                bv[n][ks] = *(const short8*)(&Bs[sl][ks][(wn * 64 + n * 16 + (lane & 15)) * 32 + roff]);
        __builtin_amdgcn_s_setprio(1);
        #pragma unroll
        for (int m = 0; m < 4; ++m)
            #pragma unroll
            for (int n = 0; n < 4; ++n)
                #pragma unroll
                for (int ks = 0; ks < 2; ++ks)
                    acc[m][n] = __builtin_amdgcn_mfma_f32_16x16x32_bf16(
                                    av[m][ks], bv[n][ks], acc[m][n], 0, 0, 0);
        __builtin_amdgcn_s_setprio(0);
    };

    // ---- prologue: stage tile 0 ----
    stageA(0, 0);
    if constexpr (B_IS_F32) {
        loadBf32(0);
        writeBf32(0);        // compiler inserts vmcnt wait for breg
        SYNC_FULL();
    } else {
        stageB16(0, 0);
        SYNC_VM0();
    }

    // ---- main loop: 8 K-steps, one barrier each, prefetch-before-compute ----
    #pragma unroll
    for (int kt = 0; kt < 8; ++kt) {
        const int sl = kt & 1;
        if (kt < 7) {
            stageA(sl ^ 1, (kt + 1) * 64);
            if constexpr (B_IS_F32) loadBf32((kt + 1) * 64);
            else                    stageB16(sl ^ 1, (kt + 1) * 64);
        }
        compute(sl);
        if (kt < 7) {
            if constexpr (B_IS_F32) {
                writeBf32(sl ^ 1);   // write-late: after compute, before barrier
                SYNC_FULL();
            } else {
                SYNC_VM0();
            }
        }
    }

    // ---- epilogue: C/D layout col = lane&15, row = (lane>>4)*4 + reg ----
    int r0 = R0 + wm * 64 + (lane >> 4) * 4;
    int c0 = C0 + wn * 64 + (lane & 15);
    if constexpr (OUT_F32) {
        float* D = (float*)Dall + imgoff;
        #pragma unroll
        for (int fm = 0; fm < 4; ++fm)
            #pragma unroll
            for (int fn = 0; fn < 4; ++fn)
                #pragma unroll
                for (int r = 0; r < 4; ++r)
                    D[(size_t)(r0 + fm * 16 + r) * 512 + c0 + fn * 16] = acc[fm][fn][r];
    } else {
        unsigned short* D = (unsigned short*)Dall + imgoff;
        #pragma unroll
        for (int fm = 0; fm < 4; ++fm)
            #pragma unroll
            for (int fn = 0; fn < 4; ++fn)
                #pragma unroll
                for (int r = 0; r < 4; ++r)
                    D[(size_t)(r0 + fm * 16 + r) * 512 + c0 + fn * 16] = f2bf(acc[fm][fn][r]);
    }
}

__global__ __launch_bounds__(256) void dct_gemm_s1(
    const unsigned short* __restrict__ A, const float* __restrict__ B,
    unsigned short* __restrict__ D) {
    dct_gemm_body<true, false>(A, B, D);
}

__global__ __launch_bounds__(256) void dct_gemm_s2(
    const unsigned short* __restrict__ A, const unsigned short* __restrict__ B,
    float* __restrict__ D) {
    dct_gemm_body<false, true>(A, B, D);
}

extern "C" void kernel_launch(void* const* d_in, const int* in_sizes, int n_in,
                              void* d_out, int out_size, void* d_ws, size_t ws_size,
                              hipStream_t stream) {
    const float* x = (const float*)d_in[0];
    float* out = (float*)d_out;

    // ws layout: [0, 512KB) = C matrix bf16; [1MB, 1MB+128MB) = intermediate T' bf16
    unsigned short* Cm = (unsigned short*)d_ws;
    unsigned short* Tm = (unsigned short*)((char*)d_ws + (1 << 20));

    int nimg = in_sizes[0] / (512 * 512);   // 256

    make_dct_mat<<<dim3(1024), dim3(256), 0, stream>>>(Cm);
    // Stage 1: T'[b] = C * X[b]^T   (B = fp32 -> cvt in regs -> bf16 LDS, out = bf16)
    dct_gemm_s1<<<dim3(nimg * 16), dim3(256), 0, stream>>>(Cm, x, Tm);
    // Stage 2: Y[b] = C * T'[b]^T = C X C^T  (B = bf16 via global_load_lds, out = fp32)
    dct_gemm_s2<<<dim3(nimg * 16), dim3(256), 0, stream>>>(Cm, Tm, out);
}